// Round 4
// baseline (220.486 us; speedup 1.0000x reference)
//
#include <hip/hip_runtime.h>
#include <hip/hip_bf16.h>
#include <cstddef>

// ---------------------------------------------------------------------------
// HardActor: fused regime-routed MLP (bf16 MFMA end-to-end)
//   h     = relu(x @ W1 + b1)            [B,256]
//   feats = relu(h @ W2 + b2)            [B,256]
//   raw   = feats @ Wh[regime] + bh[regime]   (regime = (int)x[:,255])
//   mean  = 0.1 * raw ; std = clip(exp(log_std),1e-3,1) broadcast
//
// R4: cross-tile software pipeline. Grid 512 blocks x 2 row-tiles each.
// Tile t+1's x is loaded into registers right after tile t's stage barrier,
// so its HBM latency hides under G1+G2+G3 of tile t. std written for both
// tiles up-front. Weights stay fragment-contiguous (R3). 2 blocks/CU.
// ---------------------------------------------------------------------------

typedef unsigned short u16;
typedef unsigned int   u32;

using bf16x8 = __attribute__((ext_vector_type(8))) __bf16;
using f32x4  = __attribute__((ext_vector_type(4))) float;

#define BM      64
#define LDSW    264   // 256 + 8 bf16 pad: 16B row alignment, breaks bank aliasing
#define THREADS 512
#define TILES   2

__device__ __forceinline__ u16 f2bf(float f) {
  union { float f; u32 u; } v; v.f = f;
  u32 u = v.u;
  return (u16)((u + 0x7FFFu + ((u >> 16) & 1u)) >> 16);
}

// Packed ws layout (u16 elements), fragment order for 8-wave blocks:
//  W1p [0)      : [w:8][nb:2][kk:8][lane:64][j:8]   (65536)  n=w*32+nb*16+(l&15), k=kk*32+(l>>4)*8+j
//  W2p [65536)  : same                               (65536)
//  Whp [131072) : [w:8][nb:4][kk:8][lane:64][j:8]   (131072) c=w*64+nb*16+(l&15) -> head c>>7, a=c&127
__global__ void prep_weights(const float* __restrict__ W1,
                             const float* __restrict__ W2,
                             const float* __restrict__ Wh,
                             u16* __restrict__ ws) {
  int i = blockIdx.x * 256 + threadIdx.x;          // [0, 65536)
  {
    int j  = i & 7, l = (i >> 3) & 63, kk = (i >> 9) & 7;
    int nb = (i >> 12) & 1, w = i >> 13;
    int n = w * 32 + nb * 16 + (l & 15);
    int k = kk * 32 + ((l >> 4) << 3) + j;
    ws[i]         = f2bf(W1[k * 256 + n]);
    ws[65536 + i] = f2bf(W2[k * 256 + n]);
  }
#pragma unroll
  for (int t = 0; t < 2; ++t) {
    int idx = i + t * 65536;                        // [0, 131072)
    int j  = idx & 7, l = (idx >> 3) & 63, kk = (idx >> 9) & 7;
    int nb = (idx >> 12) & 3, w = idx >> 14;
    int c = w * 64 + nb * 16 + (l & 15);            // col in [0,512)
    int k = kk * 32 + ((l >> 4) << 3) + j;
    int r = c >> 7, a = c & 127;
    ws[131072 + idx] = f2bf(Wh[(r * 256 + k) * 128 + a]);
  }
}

__device__ __forceinline__ void load_bfrags16(bf16x8 b[2][8], const u16* __restrict__ Wp,
                                              int lane) {
#pragma unroll
  for (int nb = 0; nb < 2; ++nb)
#pragma unroll
    for (int kk = 0; kk < 8; ++kk)
      b[nb][kk] = *(const bf16x8*)&Wp[(((nb * 8) + kk) * 64 + lane) * 8];
}

__device__ __forceinline__ void mfma_256(f32x4 acc[4][2], const u16* A,
                                         const bf16x8 b[2][8], int ar, int kg) {
#pragma unroll
  for (int kk = 0; kk < 8; ++kk) {
    const int k = kk * 32 + kg;
    bf16x8 a[4];
#pragma unroll
    for (int m = 0; m < 4; ++m)
      a[m] = *(const bf16x8*)&A[(m * 16 + ar) * LDSW + k];
#pragma unroll
    for (int m = 0; m < 4; ++m)
#pragma unroll
      for (int nb = 0; nb < 2; ++nb)
        acc[m][nb] = __builtin_amdgcn_mfma_f32_16x16x32_bf16(a[m], b[nb][kk], acc[m][nb], 0, 0, 0);
  }
}

__device__ __forceinline__ void epilogue_relu(f32x4 acc[4][2], const float* __restrict__ bias,
                                              u16* O, int n0, int ar, int orow) {
#pragma unroll
  for (int nb = 0; nb < 2; ++nb) {
    const int col = n0 + nb * 16 + ar;
    const float bv = bias[col];
#pragma unroll
    for (int m = 0; m < 4; ++m) {
#pragma unroll
      for (int j = 0; j < 4; ++j) {
        float v = acc[m][nb][j] + bv;
        v = v > 0.f ? v : 0.f;
        O[(m * 16 + orow + j) * LDSW + col] = f2bf(v);
      }
    }
  }
}

__global__ __launch_bounds__(THREADS, 4) void actor_main(
    const float* __restrict__ x,
    const float* __restrict__ b1, const float* __restrict__ b2,
    const float* __restrict__ bh, const float* __restrict__ log_std,
    const u16* __restrict__ wbf,
    float* __restrict__ out_mean, float* __restrict__ out_std) {
  __shared__ u16 bufA[BM * LDSW];   // x, later feats
  __shared__ u16 bufB[BM * LDSW];   // h
  __shared__ int s_regime[BM];

  const int tid  = threadIdx.x;
  const int lane = tid & 63;
  const int wave = tid >> 6;
  const int tile0 = blockIdx.x * TILES;
  const int ar   = lane & 15;          // row/col within 16-frag
  const int kg   = (lane >> 4) * 8;    // k sub-offset within 32-chunk
  const int orow = (lane >> 4) * 4;    // C/D row group
  const int n0   = wave * 32;          // GEMM1/2 col base

  // ---- prologue: issue tile0 x loads + GEMM1 B-frags (all global-only) ----
  float4 px[8];
  {
    const float4* xg = (const float4*)(x + (size_t)tile0 * BM * 256);
#pragma unroll
    for (int it = 0; it < 8; ++it) px[it] = xg[tid + it * THREADS];
  }
  bf16x8 bw1[2][8];
  load_bfrags16(bw1, wbf + wave * 8192, lane);

  // ---- std writes for ALL tiles up front (independent of everything) ----
  {
    const int c4 = (tid & 31) << 2;
    float4 s;
    s.x = fminf(fmaxf(expf(log_std[c4 + 0]), 1e-3f), 1.0f);
    s.y = fminf(fmaxf(expf(log_std[c4 + 1]), 1e-3f), 1.0f);
    s.z = fminf(fmaxf(expf(log_std[c4 + 2]), 1e-3f), 1.0f);
    s.w = fminf(fmaxf(expf(log_std[c4 + 3]), 1e-3f), 1.0f);
#pragma unroll
    for (int i = tid; i < TILES * BM * 32; i += THREADS) {   // 8 iters
      int row = i >> 5;
      *(float4*)&out_std[((size_t)tile0 * BM + row) * 128 + c4] = s;
    }
  }

  for (int t = 0; t < TILES; ++t) {
    const int row0 = (tile0 + t) * BM;

    // ---- stage x(t): convert prefetched registers -> bf16 LDS ----
#pragma unroll
    for (int it = 0; it < 8; ++it) {
      const int i = tid + it * THREADS;
      float4 v = px[it];
      int row = i >> 6, c4 = (i & 63) << 2;
      ushort4 b;
      b.x = f2bf(v.x); b.y = f2bf(v.y); b.z = f2bf(v.z); b.w = f2bf(v.w);
      *(ushort4*)&bufA[row * LDSW + c4] = b;
      if (c4 == 252) s_regime[row] = (int)v.w;
    }
    __syncthreads();

    // ---- prefetch x(t+1): latency hides under G1+G2+G3 ----
    if (t + 1 < TILES) {
      const float4* xg = (const float4*)(x + (size_t)(tile0 + t + 1) * BM * 256);
#pragma unroll
      for (int it = 0; it < 8; ++it) px[it] = xg[tid + it * THREADS];
    }

    // ---- GEMM1: x @ W1 -> h (bufB) ----
    {
      f32x4 acc[4][2] = {};
      mfma_256(acc, bufA, bw1, ar, kg);
      epilogue_relu(acc, b1, bufB, n0, ar, orow);
    }
    // GEMM2 B-frags: issue during G1 epilogue + barrier
    bf16x8 bw2[2][8];
    load_bfrags16(bw2, wbf + 65536 + wave * 8192, lane);
    __syncthreads();

    // ---- GEMM2: h @ W2 -> feats (bufA) ----
    {
      f32x4 acc[4][2] = {};
      mfma_256(acc, bufB, bw2, ar, kg);
      epilogue_relu(acc, b2, bufA, n0, ar, orow);
    }
    // reload GEMM1 B-frags for the next tile during G2 epilogue + G3
    if (t + 1 < TILES) load_bfrags16(bw1, wbf + wave * 8192, lane);
    __syncthreads();

    // ---- GEMM3: feats @ Whp (N=512, 4 heads concat); wave w owns head w>>1 ----
    {
      const u16* __restrict__ Wp3 = wbf + 131072 + wave * 16384;
      f32x4 acc[4][4] = {};
#pragma unroll 2
      for (int kk = 0; kk < 8; ++kk) {
        const int k = kk * 32 + kg;
        bf16x8 a[4], b[4];
#pragma unroll
        for (int nb = 0; nb < 4; ++nb)
          b[nb] = *(const bf16x8*)&Wp3[((nb * 8 + kk) * 64 + lane) * 8];
#pragma unroll
        for (int m = 0; m < 4; ++m)
          a[m] = *(const bf16x8*)&bufA[(m * 16 + ar) * LDSW + k];
#pragma unroll
        for (int m = 0; m < 4; ++m)
#pragma unroll
          for (int nb = 0; nb < 4; ++nb)
            acc[m][nb] = __builtin_amdgcn_mfma_f32_16x16x32_bf16(a[m], b[nb], acc[m][nb], 0, 0, 0);
      }
      const int head = wave >> 1;
      const int c0   = (wave & 1) * 64;
#pragma unroll
      for (int nb = 0; nb < 4; ++nb) {
        const int acol = c0 + nb * 16 + ar;           // 0..127 within head
        const float bhv = bh[head * 128 + acol];
#pragma unroll
        for (int m = 0; m < 4; ++m) {
#pragma unroll
          for (int j = 0; j < 4; ++j) {
            const int row = m * 16 + orow + j;
            if (s_regime[row] == head)
              out_mean[(size_t)(row0 + row) * 128 + acol] = 0.1f * (acc[m][nb][j] + bhv);
          }
        }
      }
    }
    __syncthreads();   // frees bufA (feats) + s_regime for next tile's staging
  }
}

extern "C" void kernel_launch(void* const* d_in, const int* in_sizes, int n_in,
                              void* d_out, int out_size, void* d_ws, size_t ws_size,
                              hipStream_t stream) {
  const float* x  = (const float*)d_in[0];
  const float* W1 = (const float*)d_in[1];
  const float* b1 = (const float*)d_in[2];
  const float* W2 = (const float*)d_in[3];
  const float* b2 = (const float*)d_in[4];
  const float* Wh = (const float*)d_in[5];
  const float* bh = (const float*)d_in[6];
  const float* ls = (const float*)d_in[7];

  const int B = in_sizes[0] / 256;          // 65536
  float* out_mean = (float*)d_out;
  float* out_std  = out_mean + (size_t)B * 128;
  u16* wbf = (u16*)d_ws;                    // needs 512 KiB

  hipLaunchKernelGGL(prep_weights, dim3(256), dim3(256), 0, stream, W1, W2, Wh, wbf);
  hipLaunchKernelGGL(actor_main, dim3(B / (BM * TILES)), dim3(THREADS), 0, stream,
                     x, b1, b2, bh, ls, wbf, out_mean, out_std);
}

// Round 5
// 152.751 us; speedup vs baseline: 1.4434x; 1.4434x over previous
//
#include <hip/hip_runtime.h>
#include <hip/hip_bf16.h>
#include <cstddef>

// ---------------------------------------------------------------------------
// HardActor: fused regime-routed MLP (bf16 MFMA end-to-end)
//   h     = relu(x @ W1 + b1)            [B,256]
//   feats = relu(h @ W2 + b2)            [B,256]
//   raw   = feats @ Wh[regime] + bh[regime]   (regime = (int)x[:,255])
//   mean  = 0.1 * raw ; std = clip(exp(log_std),1e-3,1) broadcast
//
// R5: register-budgeted cross-tile pipeline. Grid 512 = 2 blocks/CU exactly
// (whole grid co-resident). Per block 2 tiles; x(t+1) prefetched into 32 VGPRs
// DURING G3 only (after G2 barrier). G3 split into two 32-col halves so its
// accumulator is 32 regs, paying for px. bw1/bw2 live ranges confined to
// their GEMM (reloaded per tile; L2 hits). R4's 220us spill (FETCH 249MB /
// WRITE 400MB scratch traffic) came from px+bw1+bw2+acc all live > 128 cap.
// ---------------------------------------------------------------------------

typedef unsigned short u16;
typedef unsigned int   u32;

using bf16x8 = __attribute__((ext_vector_type(8))) __bf16;
using f32x4  = __attribute__((ext_vector_type(4))) float;

#define BM      64
#define LDSW    264   // 256 + 8 bf16 pad: 16B row alignment, breaks bank aliasing
#define THREADS 512
#define TILES   2

__device__ __forceinline__ u16 f2bf(float f) {
  return __builtin_bit_cast(u16, (__bf16)f);   // native v_cvt (RNE), pairs pack
}

// Packed ws layout (u16 elements), fragment order for 8-wave blocks:
//  W1p [0)      : [w:8][nb:2][kk:8][lane:64][j:8]   (65536)  n=w*32+nb*16+(l&15), k=kk*32+(l>>4)*8+j
//  W2p [65536)  : same                               (65536)
//  Whp [131072) : [w:8][nb:4][kk:8][lane:64][j:8]   (131072) c=w*64+nb*16+(l&15) -> head c>>7, a=c&127
__global__ void prep_weights(const float* __restrict__ W1,
                             const float* __restrict__ W2,
                             const float* __restrict__ Wh,
                             u16* __restrict__ ws) {
  int i = blockIdx.x * 256 + threadIdx.x;          // [0, 65536)
  {
    int j  = i & 7, l = (i >> 3) & 63, kk = (i >> 9) & 7;
    int nb = (i >> 12) & 1, w = i >> 13;
    int n = w * 32 + nb * 16 + (l & 15);
    int k = kk * 32 + ((l >> 4) << 3) + j;
    ws[i]         = f2bf(W1[k * 256 + n]);
    ws[65536 + i] = f2bf(W2[k * 256 + n]);
  }
#pragma unroll
  for (int t = 0; t < 2; ++t) {
    int idx = i + t * 65536;                        // [0, 131072)
    int j  = idx & 7, l = (idx >> 3) & 63, kk = (idx >> 9) & 7;
    int nb = (idx >> 12) & 3, w = idx >> 14;
    int c = w * 64 + nb * 16 + (l & 15);            // col in [0,512)
    int k = kk * 32 + ((l >> 4) << 3) + j;
    int r = c >> 7, a = c & 127;
    ws[131072 + idx] = f2bf(Wh[(r * 256 + k) * 128 + a]);
  }
}

__device__ __forceinline__ void load_bfrags16(bf16x8 b[2][8], const u16* __restrict__ Wp,
                                              int lane) {
#pragma unroll
  for (int nb = 0; nb < 2; ++nb)
#pragma unroll
    for (int kk = 0; kk < 8; ++kk)
      b[nb][kk] = *(const bf16x8*)&Wp[(((nb * 8) + kk) * 64 + lane) * 8];
}

__device__ __forceinline__ void mfma_256(f32x4 acc[4][2], const u16* A,
                                         const bf16x8 b[2][8], int ar, int kg) {
#pragma unroll
  for (int kk = 0; kk < 8; ++kk) {
    const int k = kk * 32 + kg;
    bf16x8 a[4];
#pragma unroll
    for (int m = 0; m < 4; ++m)
      a[m] = *(const bf16x8*)&A[(m * 16 + ar) * LDSW + k];
#pragma unroll
    for (int m = 0; m < 4; ++m)
#pragma unroll
      for (int nb = 0; nb < 2; ++nb)
        acc[m][nb] = __builtin_amdgcn_mfma_f32_16x16x32_bf16(a[m], b[nb][kk], acc[m][nb], 0, 0, 0);
  }
}

__device__ __forceinline__ void epilogue_relu(f32x4 acc[4][2], const float* __restrict__ bias,
                                              u16* O, int n0, int ar, int orow) {
#pragma unroll
  for (int nb = 0; nb < 2; ++nb) {
    const int col = n0 + nb * 16 + ar;
    const float bv = bias[col];
#pragma unroll
    for (int m = 0; m < 4; ++m) {
#pragma unroll
      for (int j = 0; j < 4; ++j) {
        float v = acc[m][nb][j] + bv;
        v = v > 0.f ? v : 0.f;
        O[(m * 16 + orow + j) * LDSW + col] = f2bf(v);
      }
    }
  }
}

__global__ __launch_bounds__(THREADS, 4) void actor_main(
    const float* __restrict__ x,
    const float* __restrict__ b1, const float* __restrict__ b2,
    const float* __restrict__ bh, const float* __restrict__ log_std,
    const u16* __restrict__ wbf,
    float* __restrict__ out_mean, float* __restrict__ out_std) {
  __shared__ u16 bufA[BM * LDSW];   // x, later feats
  __shared__ u16 bufB[BM * LDSW];   // h
  __shared__ int s_regime[BM];

  const int tid  = threadIdx.x;
  const int lane = tid & 63;
  const int wave = tid >> 6;
  const int tile0 = blockIdx.x * TILES;
  const int ar   = lane & 15;          // row/col within 16-frag
  const int kg   = (lane >> 4) * 8;    // k sub-offset within 32-chunk
  const int orow = (lane >> 4) * 4;    // C/D row group
  const int n0   = wave * 32;          // GEMM1/2 col base

  // ---- prologue: issue tile0's x loads (consumed at first stage) ----
  float4 px[8];
  {
    const float4* xg = (const float4*)(x + (size_t)tile0 * BM * 256);
#pragma unroll
    for (int it = 0; it < 8; ++it) px[it] = xg[tid + it * THREADS];
  }

  // ---- std writes for both tiles up front (independent of everything) ----
  {
    const int c4 = (tid & 31) << 2;
    float4 s;
    s.x = fminf(fmaxf(expf(log_std[c4 + 0]), 1e-3f), 1.0f);
    s.y = fminf(fmaxf(expf(log_std[c4 + 1]), 1e-3f), 1.0f);
    s.z = fminf(fmaxf(expf(log_std[c4 + 2]), 1e-3f), 1.0f);
    s.w = fminf(fmaxf(expf(log_std[c4 + 3]), 1e-3f), 1.0f);
#pragma unroll
    for (int i = tid; i < TILES * BM * 32; i += THREADS) {   // 8 iters
      int row = i >> 5;
      *(float4*)&out_std[((size_t)tile0 * BM + row) * 128 + c4] = s;
    }
  }

#pragma unroll 1
  for (int t = 0; t < TILES; ++t) {
    const int row0 = (tile0 + t) * BM;

    // ---- bw1 loads issue here; latency hides under stage + barrier ----
    bf16x8 bw1[2][8];
    load_bfrags16(bw1, wbf + wave * 8192, lane);

    // ---- stage x(t): registers -> bf16 LDS ----
#pragma unroll
    for (int it = 0; it < 8; ++it) {
      const int i = tid + it * THREADS;
      float4 v = px[it];
      int row = i >> 6, c4 = (i & 63) << 2;
      ushort4 b;
      b.x = f2bf(v.x); b.y = f2bf(v.y); b.z = f2bf(v.z); b.w = f2bf(v.w);
      *(ushort4*)&bufA[row * LDSW + c4] = b;
      if (c4 == 252) s_regime[row] = (int)v.w;
    }
    __syncthreads();

    // ---- GEMM1: x @ W1 -> h (bufB) ----
    {
      f32x4 acc[4][2] = {};
      mfma_256(acc, bufA, bw1, ar, kg);
      epilogue_relu(acc, b1, bufB, n0, ar, orow);
    }
    // bw2 loads overlap G1 epilogue + barrier (bw1 dead by now)
    bf16x8 bw2[2][8];
    load_bfrags16(bw2, wbf + 65536 + wave * 8192, lane);
    __syncthreads();

    // ---- GEMM2: h @ W2 -> feats (bufA) ----
    {
      f32x4 acc[4][2] = {};
      mfma_256(acc, bufB, bw2, ar, kg);
      epilogue_relu(acc, b2, bufA, n0, ar, orow);
    }
    __syncthreads();

    // ---- prefetch x(t+1): 32 VGPR, live only across G3 ----
    if (t + 1 < TILES) {
      const float4* xg = (const float4*)(x + (size_t)(tile0 + t + 1) * BM * 256);
#pragma unroll
      for (int it = 0; it < 8; ++it) px[it] = xg[tid + it * THREADS];
    }

    // ---- GEMM3 in two 32-col halves (acc stays at 32 regs to pay for px) ----
    {
      const u16* __restrict__ Wp3 = wbf + 131072 + wave * 16384;
      const int head = wave >> 1;
#pragma unroll 1
      for (int h3 = 0; h3 < 2; ++h3) {
        f32x4 acc[4][2] = {};
#pragma unroll 2
        for (int kk = 0; kk < 8; ++kk) {
          const int k = kk * 32 + kg;
          bf16x8 a[4], b[2];
#pragma unroll
          for (int nb = 0; nb < 2; ++nb)
            b[nb] = *(const bf16x8*)&Wp3[(((h3 * 2 + nb) * 8 + kk) * 64 + lane) * 8];
#pragma unroll
          for (int m = 0; m < 4; ++m)
            a[m] = *(const bf16x8*)&bufA[(m * 16 + ar) * LDSW + k];
#pragma unroll
          for (int m = 0; m < 4; ++m)
#pragma unroll
            for (int nb = 0; nb < 2; ++nb)
              acc[m][nb] = __builtin_amdgcn_mfma_f32_16x16x32_bf16(a[m], b[nb], acc[m][nb], 0, 0, 0);
        }
#pragma unroll
        for (int nb = 0; nb < 2; ++nb) {
          const int acol = (wave & 1) * 64 + h3 * 32 + nb * 16 + ar;  // 0..127 in head
          const float bhv = bh[head * 128 + acol];
#pragma unroll
          for (int m = 0; m < 4; ++m) {
#pragma unroll
            for (int j = 0; j < 4; ++j) {
              const int row = m * 16 + orow + j;
              if (s_regime[row] == head)
                out_mean[(size_t)(row0 + row) * 128 + acol] = 0.1f * (acc[m][nb][j] + bhv);
            }
          }
        }
      }
    }
    __syncthreads();   // frees bufA (feats) + s_regime for next tile's staging
  }
}

extern "C" void kernel_launch(void* const* d_in, const int* in_sizes, int n_in,
                              void* d_out, int out_size, void* d_ws, size_t ws_size,
                              hipStream_t stream) {
  const float* x  = (const float*)d_in[0];
  const float* W1 = (const float*)d_in[1];
  const float* b1 = (const float*)d_in[2];
  const float* W2 = (const float*)d_in[3];
  const float* b2 = (const float*)d_in[4];
  const float* Wh = (const float*)d_in[5];
  const float* bh = (const float*)d_in[6];
  const float* ls = (const float*)d_in[7];

  const int B = in_sizes[0] / 256;          // 65536
  float* out_mean = (float*)d_out;
  float* out_std  = out_mean + (size_t)B * 128;
  u16* wbf = (u16*)d_ws;                    // needs 512 KiB

  hipLaunchKernelGGL(prep_weights, dim3(256), dim3(256), 0, stream, W1, W2, Wh, wbf);
  hipLaunchKernelGGL(actor_main, dim3(B / (BM * TILES)), dim3(THREADS), 0, stream,
                     x, b1, b2, bh, ls, wbf, out_mean, out_std);
}

// Round 6
// 99.485 us; speedup vs baseline: 2.2163x; 1.5354x over previous
//
#include <hip/hip_runtime.h>
#include <hip/hip_bf16.h>
#include <cstddef>

// ---------------------------------------------------------------------------
// HardActor: fused regime-routed MLP (bf16 MFMA end-to-end)
//   h     = relu(x @ W1 + b1)            [B,256]
//   feats = relu(h @ W2 + b2)            [B,256]
//   raw   = feats @ Wh[regime] + bh[regime]   (regime = (int)x[:,255])
//   mean  = 0.1 * raw ; std = clip(exp(log_std),1e-3,1) broadcast
//
// R6: back to R3's no-spill structure (register prefetch abandoned — the
// allocator pins 64 VGPR and spills instead of growing; R4/R5 FETCH/WRITE
// inflation proved it). Occupancy attack instead: BM 64->32 halves LDS to
// 34KB -> 4 blocks/CU (32-wave cap, was 16). Grid 2048, launch_bounds(512,8)
// pins VGPR<=64 (R3 measured 64 at HIGHER pressure). Phases half as long,
// 2x cross-block overlap hides barrier drains + LDS/global latency.
// ---------------------------------------------------------------------------

typedef unsigned short u16;
typedef unsigned int   u32;

using bf16x8 = __attribute__((ext_vector_type(8))) __bf16;
using f32x4  = __attribute__((ext_vector_type(4))) float;

#define BM      32
#define LDSW    264   // 256 + 8 bf16 pad: 16B row alignment, breaks bank aliasing
#define THREADS 512

__device__ __forceinline__ u16 f2bf(float f) {
  return __builtin_bit_cast(u16, (__bf16)f);   // native v_cvt (RNE)
}

// Packed ws layout (u16 elements), fragment order for 8-wave blocks:
//  W1p [0)      : [w:8][nb:2][kk:8][lane:64][j:8]   (65536)  n=w*32+nb*16+(l&15), k=kk*32+(l>>4)*8+j
//  W2p [65536)  : same                               (65536)
//  Whp [131072) : [w:8][nb:4][kk:8][lane:64][j:8]   (131072) c=w*64+nb*16+(l&15) -> head c>>7, a=c&127
__global__ void prep_weights(const float* __restrict__ W1,
                             const float* __restrict__ W2,
                             const float* __restrict__ Wh,
                             u16* __restrict__ ws) {
  int i = blockIdx.x * 256 + threadIdx.x;          // [0, 65536)
  {
    int j  = i & 7, l = (i >> 3) & 63, kk = (i >> 9) & 7;
    int nb = (i >> 12) & 1, w = i >> 13;
    int n = w * 32 + nb * 16 + (l & 15);
    int k = kk * 32 + ((l >> 4) << 3) + j;
    ws[i]         = f2bf(W1[k * 256 + n]);
    ws[65536 + i] = f2bf(W2[k * 256 + n]);
  }
#pragma unroll
  for (int t = 0; t < 2; ++t) {
    int idx = i + t * 65536;                        // [0, 131072)
    int j  = idx & 7, l = (idx >> 3) & 63, kk = (idx >> 9) & 7;
    int nb = (idx >> 12) & 3, w = idx >> 14;
    int c = w * 64 + nb * 16 + (l & 15);            // col in [0,512)
    int k = kk * 32 + ((l >> 4) << 3) + j;
    int r = c >> 7, a = c & 127;
    ws[131072 + idx] = f2bf(Wh[(r * 256 + k) * 128 + a]);
  }
}

// 32x(32 cols)xK=256 GEMM slice for one wave; b-frag loads inside the kk loop
// so the compiler can sink them (keeps VGPR <= 64).
__device__ __forceinline__ void gemm32(f32x4 acc[2][2], const u16* A,
                                       const u16* __restrict__ Wp,
                                       int ar, int kg, int lane) {
#pragma unroll
  for (int kk = 0; kk < 8; ++kk) {
    const int k = kk * 32 + kg;
    bf16x8 a[2], b[2];
#pragma unroll
    for (int m = 0; m < 2; ++m)
      a[m] = *(const bf16x8*)&A[(m * 16 + ar) * LDSW + k];
#pragma unroll
    for (int nb = 0; nb < 2; ++nb)
      b[nb] = *(const bf16x8*)&Wp[((nb * 8 + kk) * 64 + lane) * 8];
#pragma unroll
    for (int m = 0; m < 2; ++m)
#pragma unroll
      for (int nb = 0; nb < 2; ++nb)
        acc[m][nb] = __builtin_amdgcn_mfma_f32_16x16x32_bf16(a[m], b[nb], acc[m][nb], 0, 0, 0);
  }
}

__device__ __forceinline__ void epilogue_relu(f32x4 acc[2][2], const float* __restrict__ bias,
                                              u16* O, int n0, int ar, int orow) {
#pragma unroll
  for (int nb = 0; nb < 2; ++nb) {
    const int col = n0 + nb * 16 + ar;
    const float bv = bias[col];
#pragma unroll
    for (int m = 0; m < 2; ++m) {
#pragma unroll
      for (int j = 0; j < 4; ++j) {
        float v = acc[m][nb][j] + bv;
        v = v > 0.f ? v : 0.f;
        O[(m * 16 + orow + j) * LDSW + col] = f2bf(v);
      }
    }
  }
}

__global__ __launch_bounds__(THREADS, 8) void actor_main(
    const float* __restrict__ x,
    const float* __restrict__ b1, const float* __restrict__ b2,
    const float* __restrict__ bh, const float* __restrict__ log_std,
    const u16* __restrict__ wbf,
    float* __restrict__ out_mean, float* __restrict__ out_std) {
  __shared__ u16 bufA[BM * LDSW];   // x, later feats
  __shared__ u16 bufB[BM * LDSW];   // h
  __shared__ int s_regime[BM];

  const int tid  = threadIdx.x;
  const int lane = tid & 63;
  const int wave = tid >> 6;
  const int row0 = blockIdx.x * BM;
  const int ar   = lane & 15;          // row/col within 16-frag
  const int kg   = (lane >> 4) * 8;    // k sub-offset within 32-chunk
  const int orow = (lane >> 4) * 4;    // C/D row group
  const int n0   = wave * 32;          // GEMM1/2 col base

  // ---- stage x -> bf16 LDS; capture regime from col 255 ----
  {
    const float4* xg = (const float4*)(x + (size_t)row0 * 256);
#pragma unroll
    for (int it = 0; it < 4; ++it) {              // BM*64/THREADS = 4
      const int i = tid + it * THREADS;
      float4 v = xg[i];
      int row = i >> 6, c4 = (i & 63) << 2;
      ushort4 b;
      b.x = f2bf(v.x); b.y = f2bf(v.y); b.z = f2bf(v.z); b.w = f2bf(v.w);
      *(ushort4*)&bufA[row * LDSW + c4] = b;
      if (c4 == 252) s_regime[row] = (int)v.w;
    }
  }

  // ---- std writes (independent of GEMMs; overlap the barrier wait) ----
  {
    const int c4 = (tid & 31) << 2;
    float4 s;
    s.x = fminf(fmaxf(expf(log_std[c4 + 0]), 1e-3f), 1.0f);
    s.y = fminf(fmaxf(expf(log_std[c4 + 1]), 1e-3f), 1.0f);
    s.z = fminf(fmaxf(expf(log_std[c4 + 2]), 1e-3f), 1.0f);
    s.w = fminf(fmaxf(expf(log_std[c4 + 3]), 1e-3f), 1.0f);
#pragma unroll
    for (int i = tid; i < BM * 32; i += THREADS) {   // 2 iters
      int row = i >> 5;
      *(float4*)&out_std[(size_t)(row0 + row) * 128 + c4] = s;
    }
  }
  __syncthreads();

  // ---- GEMM1: x @ W1 -> h (bufB) ----
  {
    f32x4 acc[2][2] = {};
    gemm32(acc, bufA, wbf + wave * 8192, ar, kg, lane);
    epilogue_relu(acc, b1, bufB, n0, ar, orow);
  }
  __syncthreads();

  // ---- GEMM2: h @ W2 -> feats (bufA) ----
  {
    f32x4 acc[2][2] = {};
    gemm32(acc, bufB, wbf + 65536 + wave * 8192, ar, kg, lane);
    epilogue_relu(acc, b2, bufA, n0, ar, orow);
  }
  __syncthreads();

  // ---- GEMM3: feats @ Whp (N=512, 4 heads concat); wave w owns head w>>1 ----
  {
    const u16* __restrict__ Wp3 = wbf + 131072 + wave * 16384;
    f32x4 acc[2][4] = {};
#pragma unroll
    for (int kk = 0; kk < 8; ++kk) {
      const int k = kk * 32 + kg;
      bf16x8 a[2], b[4];
#pragma unroll
      for (int nb = 0; nb < 4; ++nb)
        b[nb] = *(const bf16x8*)&Wp3[((nb * 8 + kk) * 64 + lane) * 8];
#pragma unroll
      for (int m = 0; m < 2; ++m)
        a[m] = *(const bf16x8*)&bufA[(m * 16 + ar) * LDSW + k];
#pragma unroll
      for (int m = 0; m < 2; ++m)
#pragma unroll
        for (int nb = 0; nb < 4; ++nb)
          acc[m][nb] = __builtin_amdgcn_mfma_f32_16x16x32_bf16(a[m], b[nb], acc[m][nb], 0, 0, 0);
    }
    const int head = wave >> 1;
    const int c0   = (wave & 1) * 64;
#pragma unroll
    for (int nb = 0; nb < 4; ++nb) {
      const int acol = c0 + nb * 16 + ar;           // 0..127 within head
      const float bhv = bh[head * 128 + acol];
#pragma unroll
      for (int m = 0; m < 2; ++m) {
#pragma unroll
        for (int j = 0; j < 4; ++j) {
          const int row = m * 16 + orow + j;
          if (s_regime[row] == head)
            out_mean[(size_t)(row0 + row) * 128 + acol] = 0.1f * (acc[m][nb][j] + bhv);
        }
      }
    }
  }
}

extern "C" void kernel_launch(void* const* d_in, const int* in_sizes, int n_in,
                              void* d_out, int out_size, void* d_ws, size_t ws_size,
                              hipStream_t stream) {
  const float* x  = (const float*)d_in[0];
  const float* W1 = (const float*)d_in[1];
  const float* b1 = (const float*)d_in[2];
  const float* W2 = (const float*)d_in[3];
  const float* b2 = (const float*)d_in[4];
  const float* Wh = (const float*)d_in[5];
  const float* bh = (const float*)d_in[6];
  const float* ls = (const float*)d_in[7];

  const int B = in_sizes[0] / 256;          // 65536
  float* out_mean = (float*)d_out;
  float* out_std  = out_mean + (size_t)B * 128;
  u16* wbf = (u16*)d_ws;                    // needs 512 KiB

  hipLaunchKernelGGL(prep_weights, dim3(256), dim3(256), 0, stream, W1, W2, Wh, wbf);
  hipLaunchKernelGGL(actor_main, dim3(B / BM), dim3(THREADS), 0, stream,
                     x, b1, b2, bh, ls, wbf, out_mean, out_std);
}

// Round 7
// 81.530 us; speedup vs baseline: 2.7043x; 1.2202x over previous
//
#include <hip/hip_runtime.h>
#include <hip/hip_bf16.h>
#include <cstddef>

// ---------------------------------------------------------------------------
// HardActor: fused regime-routed MLP (bf16 MFMA end-to-end)
//   h     = relu(x @ W1 + b1)            [B,256]
//   feats = relu(h @ W2 + b2)            [B,256]
//   raw   = feats @ Wh[regime] + bh[regime]   (regime = (int)x[:,255])
//   mean  = 0.1 * raw ; std = clip(exp(log_std),1e-3,1) broadcast
//
// R7: R6 with __launch_bounds__(512,4). R6's (512,8) forced a 32-VGPR budget
// and the allocator spilled (FETCH 86MB / WRITE 191MB scratch signature,
// VGPR_Count=32). (512,4) is R3's proven no-spill setting (VGPR=64, which
// still permits 8 waves/SIMD); BM=32's 34KB LDS still allows 4 blocks/CU,
// so we keep R6's occupancy gain without the spill.
// ---------------------------------------------------------------------------

typedef unsigned short u16;
typedef unsigned int   u32;

using bf16x8 = __attribute__((ext_vector_type(8))) __bf16;
using f32x4  = __attribute__((ext_vector_type(4))) float;

#define BM      32
#define LDSW    264   // 256 + 8 bf16 pad: 16B row alignment, breaks bank aliasing
#define THREADS 512

__device__ __forceinline__ u16 f2bf(float f) {
  return __builtin_bit_cast(u16, (__bf16)f);   // native v_cvt (RNE)
}

// Packed ws layout (u16 elements), fragment order for 8-wave blocks:
//  W1p [0)      : [w:8][nb:2][kk:8][lane:64][j:8]   (65536)  n=w*32+nb*16+(l&15), k=kk*32+(l>>4)*8+j
//  W2p [65536)  : same                               (65536)
//  Whp [131072) : [w:8][nb:4][kk:8][lane:64][j:8]   (131072) c=w*64+nb*16+(l&15) -> head c>>7, a=c&127
__global__ void prep_weights(const float* __restrict__ W1,
                             const float* __restrict__ W2,
                             const float* __restrict__ Wh,
                             u16* __restrict__ ws) {
  int i = blockIdx.x * 256 + threadIdx.x;          // [0, 65536)
  {
    int j  = i & 7, l = (i >> 3) & 63, kk = (i >> 9) & 7;
    int nb = (i >> 12) & 1, w = i >> 13;
    int n = w * 32 + nb * 16 + (l & 15);
    int k = kk * 32 + ((l >> 4) << 3) + j;
    ws[i]         = f2bf(W1[k * 256 + n]);
    ws[65536 + i] = f2bf(W2[k * 256 + n]);
  }
#pragma unroll
  for (int t = 0; t < 2; ++t) {
    int idx = i + t * 65536;                        // [0, 131072)
    int j  = idx & 7, l = (idx >> 3) & 63, kk = (idx >> 9) & 7;
    int nb = (idx >> 12) & 3, w = idx >> 14;
    int c = w * 64 + nb * 16 + (l & 15);            // col in [0,512)
    int k = kk * 32 + ((l >> 4) << 3) + j;
    int r = c >> 7, a = c & 127;
    ws[131072 + idx] = f2bf(Wh[(r * 256 + k) * 128 + a]);
  }
}

// 32x(32 cols)xK=256 GEMM slice for one wave; b-frag loads inside the kk loop
// so the compiler can sink them (keeps VGPR <= 64).
__device__ __forceinline__ void gemm32(f32x4 acc[2][2], const u16* A,
                                       const u16* __restrict__ Wp,
                                       int ar, int kg, int lane) {
#pragma unroll
  for (int kk = 0; kk < 8; ++kk) {
    const int k = kk * 32 + kg;
    bf16x8 a[2], b[2];
#pragma unroll
    for (int m = 0; m < 2; ++m)
      a[m] = *(const bf16x8*)&A[(m * 16 + ar) * LDSW + k];
#pragma unroll
    for (int nb = 0; nb < 2; ++nb)
      b[nb] = *(const bf16x8*)&Wp[((nb * 8 + kk) * 64 + lane) * 8];
#pragma unroll
    for (int m = 0; m < 2; ++m)
#pragma unroll
      for (int nb = 0; nb < 2; ++nb)
        acc[m][nb] = __builtin_amdgcn_mfma_f32_16x16x32_bf16(a[m], b[nb], acc[m][nb], 0, 0, 0);
  }
}

__device__ __forceinline__ void epilogue_relu(f32x4 acc[2][2], const float* __restrict__ bias,
                                              u16* O, int n0, int ar, int orow) {
#pragma unroll
  for (int nb = 0; nb < 2; ++nb) {
    const int col = n0 + nb * 16 + ar;
    const float bv = bias[col];
#pragma unroll
    for (int m = 0; m < 2; ++m) {
#pragma unroll
      for (int j = 0; j < 4; ++j) {
        float v = acc[m][nb][j] + bv;
        v = v > 0.f ? v : 0.f;
        O[(m * 16 + orow + j) * LDSW + col] = f2bf(v);
      }
    }
  }
}

__global__ __launch_bounds__(THREADS, 4) void actor_main(
    const float* __restrict__ x,
    const float* __restrict__ b1, const float* __restrict__ b2,
    const float* __restrict__ bh, const float* __restrict__ log_std,
    const u16* __restrict__ wbf,
    float* __restrict__ out_mean, float* __restrict__ out_std) {
  __shared__ u16 bufA[BM * LDSW];   // x, later feats
  __shared__ u16 bufB[BM * LDSW];   // h
  __shared__ int s_regime[BM];

  const int tid  = threadIdx.x;
  const int lane = tid & 63;
  const int wave = tid >> 6;
  const int row0 = blockIdx.x * BM;
  const int ar   = lane & 15;          // row/col within 16-frag
  const int kg   = (lane >> 4) * 8;    // k sub-offset within 32-chunk
  const int orow = (lane >> 4) * 4;    // C/D row group
  const int n0   = wave * 32;          // GEMM1/2 col base

  // ---- stage x -> bf16 LDS; capture regime from col 255 ----
  {
    const float4* xg = (const float4*)(x + (size_t)row0 * 256);
#pragma unroll
    for (int it = 0; it < 4; ++it) {              // BM*64/THREADS = 4
      const int i = tid + it * THREADS;
      float4 v = xg[i];
      int row = i >> 6, c4 = (i & 63) << 2;
      ushort4 b;
      b.x = f2bf(v.x); b.y = f2bf(v.y); b.z = f2bf(v.z); b.w = f2bf(v.w);
      *(ushort4*)&bufA[row * LDSW + c4] = b;
      if (c4 == 252) s_regime[row] = (int)v.w;
    }
  }

  // ---- std writes (independent of GEMMs; overlap the barrier wait) ----
  {
    const int c4 = (tid & 31) << 2;
    float4 s;
    s.x = fminf(fmaxf(expf(log_std[c4 + 0]), 1e-3f), 1.0f);
    s.y = fminf(fmaxf(expf(log_std[c4 + 1]), 1e-3f), 1.0f);
    s.z = fminf(fmaxf(expf(log_std[c4 + 2]), 1e-3f), 1.0f);
    s.w = fminf(fmaxf(expf(log_std[c4 + 3]), 1e-3f), 1.0f);
#pragma unroll
    for (int i = tid; i < BM * 32; i += THREADS) {   // 2 iters
      int row = i >> 5;
      *(float4*)&out_std[(size_t)(row0 + row) * 128 + c4] = s;
    }
  }
  __syncthreads();

  // ---- GEMM1: x @ W1 -> h (bufB) ----
  {
    f32x4 acc[2][2] = {};
    gemm32(acc, bufA, wbf + wave * 8192, ar, kg, lane);
    epilogue_relu(acc, b1, bufB, n0, ar, orow);
  }
  __syncthreads();

  // ---- GEMM2: h @ W2 -> feats (bufA) ----
  {
    f32x4 acc[2][2] = {};
    gemm32(acc, bufB, wbf + 65536 + wave * 8192, ar, kg, lane);
    epilogue_relu(acc, b2, bufA, n0, ar, orow);
  }
  __syncthreads();

  // ---- GEMM3: feats @ Whp (N=512, 4 heads concat); wave w owns head w>>1 ----
  {
    const u16* __restrict__ Wp3 = wbf + 131072 + wave * 16384;
    f32x4 acc[2][4] = {};
#pragma unroll
    for (int kk = 0; kk < 8; ++kk) {
      const int k = kk * 32 + kg;
      bf16x8 a[2], b[4];
#pragma unroll
      for (int nb = 0; nb < 4; ++nb)
        b[nb] = *(const bf16x8*)&Wp3[((nb * 8 + kk) * 64 + lane) * 8];
#pragma unroll
      for (int m = 0; m < 2; ++m)
        a[m] = *(const bf16x8*)&bufA[(m * 16 + ar) * LDSW + k];
#pragma unroll
      for (int m = 0; m < 2; ++m)
#pragma unroll
        for (int nb = 0; nb < 4; ++nb)
          acc[m][nb] = __builtin_amdgcn_mfma_f32_16x16x32_bf16(a[m], b[nb], acc[m][nb], 0, 0, 0);
    }
    const int head = wave >> 1;
    const int c0   = (wave & 1) * 64;
#pragma unroll
    for (int nb = 0; nb < 4; ++nb) {
      const int acol = c0 + nb * 16 + ar;           // 0..127 within head
      const float bhv = bh[head * 128 + acol];
#pragma unroll
      for (int m = 0; m < 2; ++m) {
#pragma unroll
        for (int j = 0; j < 4; ++j) {
          const int row = m * 16 + orow + j;
          if (s_regime[row] == head)
            out_mean[(size_t)(row0 + row) * 128 + acol] = 0.1f * (acc[m][nb][j] + bhv);
        }
      }
    }
  }
}

extern "C" void kernel_launch(void* const* d_in, const int* in_sizes, int n_in,
                              void* d_out, int out_size, void* d_ws, size_t ws_size,
                              hipStream_t stream) {
  const float* x  = (const float*)d_in[0];
  const float* W1 = (const float*)d_in[1];
  const float* b1 = (const float*)d_in[2];
  const float* W2 = (const float*)d_in[3];
  const float* b2 = (const float*)d_in[4];
  const float* Wh = (const float*)d_in[5];
  const float* bh = (const float*)d_in[6];
  const float* ls = (const float*)d_in[7];

  const int B = in_sizes[0] / 256;          // 65536
  float* out_mean = (float*)d_out;
  float* out_std  = out_mean + (size_t)B * 128;
  u16* wbf = (u16*)d_ws;                    // needs 512 KiB

  hipLaunchKernelGGL(prep_weights, dim3(256), dim3(256), 0, stream, W1, W2, Wh, wbf);
  hipLaunchKernelGGL(actor_main, dim3(B / BM), dim3(THREADS), 0, stream,
                     x, b1, b2, bh, ls, wbf, out_mean, out_std);
}

// Round 8
// 70.826 us; speedup vs baseline: 3.1130x; 1.1511x over previous
//
#include <hip/hip_runtime.h>
#include <hip/hip_bf16.h>
#include <cstddef>

// ---------------------------------------------------------------------------
// HardActor: fused regime-routed MLP (bf16 MFMA end-to-end)
//   h     = relu(x @ W1 + b1)            [B,256]
//   feats = relu(h @ W2 + b2)            [B,256]
//   raw   = feats @ Wh[regime] + bh[regime]   (regime = (int)x[:,255])
//   mean  = 0.1 * raw ; std = clip(exp(log_std),1e-3,1) broadcast
//
// R8: BM=64 (R3's weight-traffic ratio: 8 KB/row from L2) but 16 waves/block
// (1024 threads). Waves split N 16-ways: G1/G2 16 cols/wave, G3 32 cols/wave
// (head = wave>>2). Register pressure DROPS (acc<=32 f32); LDS unchanged
// 68KB -> 2 blocks/CU -> 32-wave/CU cap. 2x independent waves per barrier
// group to hide L2 b-frag latency that R3/R7 exposed (util ~15%).
// R7 lesson kept: no cross-tile register pipelining (allocator spills).
// ---------------------------------------------------------------------------

typedef unsigned short u16;
typedef unsigned int   u32;

using bf16x8 = __attribute__((ext_vector_type(8))) __bf16;
using f32x4  = __attribute__((ext_vector_type(4))) float;

#define BM      64
#define LDSW    264   // 256 + 8 bf16 pad: 16B row alignment, breaks bank aliasing
#define THREADS 1024

__device__ __forceinline__ u16 f2bf(float f) {
  return __builtin_bit_cast(u16, (__bf16)f);   // native v_cvt (RNE)
}

// Packed ws layout (u16 elements), fragment order for 16-wave blocks:
//  W1p [0)      : [w:16][kk:8][lane:64][j:8]        (65536)  n=w*16+(l&15), k=kk*32+(l>>4)*8+j
//  W2p [65536)  : same                               (65536)
//  Whp [131072) : [w:16][nb:2][kk:8][lane:64][j:8]  (131072) c=w*32+nb*16+(l&15) -> head c>>7, a=c&127
__global__ void prep_weights(const float* __restrict__ W1,
                             const float* __restrict__ W2,
                             const float* __restrict__ Wh,
                             u16* __restrict__ ws) {
  int i = blockIdx.x * 256 + threadIdx.x;          // [0, 65536)
  {
    int j  = i & 7, l = (i >> 3) & 63, kk = (i >> 9) & 7;
    int w  = (i >> 12) & 15;
    int n = w * 16 + (l & 15);
    int k = kk * 32 + ((l >> 4) << 3) + j;
    ws[i]         = f2bf(W1[k * 256 + n]);
    ws[65536 + i] = f2bf(W2[k * 256 + n]);
  }
#pragma unroll
  for (int t = 0; t < 2; ++t) {
    int idx = i + t * 65536;                        // [0, 131072)
    int j  = idx & 7, l = (idx >> 3) & 63, kk = (idx >> 9) & 7;
    int nb = (idx >> 12) & 1, w = (idx >> 13) & 15;
    int c = w * 32 + nb * 16 + (l & 15);            // col in [0,512)
    int k = kk * 32 + ((l >> 4) << 3) + j;
    int r = c >> 7, a = c & 127;
    ws[131072 + idx] = f2bf(Wh[(r * 256 + k) * 128 + a]);
  }
}

// 64x(16 cols)xK=256 GEMM slice for one wave (16-way N-split).
__device__ __forceinline__ void gemm16(f32x4 acc[4], const u16* A,
                                       const u16* __restrict__ Wp,
                                       int ar, int kg, int lane) {
#pragma unroll
  for (int kk = 0; kk < 8; ++kk) {
    const int k = kk * 32 + kg;
    bf16x8 b = *(const bf16x8*)&Wp[(kk * 64 + lane) * 8];
    bf16x8 a[4];
#pragma unroll
    for (int m = 0; m < 4; ++m)
      a[m] = *(const bf16x8*)&A[(m * 16 + ar) * LDSW + k];
#pragma unroll
    for (int m = 0; m < 4; ++m)
      acc[m] = __builtin_amdgcn_mfma_f32_16x16x32_bf16(a[m], b, acc[m], 0, 0, 0);
  }
}

__device__ __forceinline__ void epilogue_relu(f32x4 acc[4], const float* __restrict__ bias,
                                              u16* O, int col, int orow) {
  const float bv = bias[col];
#pragma unroll
  for (int m = 0; m < 4; ++m) {
#pragma unroll
    for (int j = 0; j < 4; ++j) {
      float v = acc[m][j] + bv;
      v = v > 0.f ? v : 0.f;
      O[(m * 16 + orow + j) * LDSW + col] = f2bf(v);
    }
  }
}

__global__ __launch_bounds__(THREADS, 4) void actor_main(
    const float* __restrict__ x,
    const float* __restrict__ b1, const float* __restrict__ b2,
    const float* __restrict__ bh, const float* __restrict__ log_std,
    const u16* __restrict__ wbf,
    float* __restrict__ out_mean, float* __restrict__ out_std) {
  __shared__ u16 bufA[BM * LDSW];   // x, later feats
  __shared__ u16 bufB[BM * LDSW];   // h
  __shared__ int s_regime[BM];

  const int tid  = threadIdx.x;
  const int lane = tid & 63;
  const int wave = tid >> 6;           // 0..15
  const int row0 = blockIdx.x * BM;
  const int ar   = lane & 15;          // row/col within 16-frag
  const int kg   = (lane >> 4) * 8;    // k sub-offset within 32-chunk
  const int orow = (lane >> 4) * 4;    // C/D row group
  const int n0   = wave * 16;          // GEMM1/2 col (16 cols/wave)

  // ---- stage x -> bf16 LDS; capture regime from col 255 ----
  {
    const float4* xg = (const float4*)(x + (size_t)row0 * 256);
#pragma unroll
    for (int it = 0; it < 4; ++it) {              // BM*64/THREADS = 4
      const int i = tid + it * THREADS;
      float4 v = xg[i];
      int row = i >> 6, c4 = (i & 63) << 2;
      ushort4 b;
      b.x = f2bf(v.x); b.y = f2bf(v.y); b.z = f2bf(v.z); b.w = f2bf(v.w);
      *(ushort4*)&bufA[row * LDSW + c4] = b;
      if (c4 == 252) s_regime[row] = (int)v.w;
    }
  }

  // ---- std writes (independent of GEMMs; overlap the barrier wait) ----
  {
    const int c4 = (tid & 31) << 2;
    float4 s;
    s.x = fminf(fmaxf(expf(log_std[c4 + 0]), 1e-3f), 1.0f);
    s.y = fminf(fmaxf(expf(log_std[c4 + 1]), 1e-3f), 1.0f);
    s.z = fminf(fmaxf(expf(log_std[c4 + 2]), 1e-3f), 1.0f);
    s.w = fminf(fmaxf(expf(log_std[c4 + 3]), 1e-3f), 1.0f);
#pragma unroll
    for (int i = tid; i < BM * 32; i += THREADS) {   // 2 iters
      int row = i >> 5;
      *(float4*)&out_std[(size_t)(row0 + row) * 128 + c4] = s;
    }
  }
  __syncthreads();

  // ---- GEMM1: x @ W1 -> h (bufB) ----
  {
    f32x4 acc[4] = {};
    gemm16(acc, bufA, wbf + wave * 4096, ar, kg, lane);
    epilogue_relu(acc, b1, bufB, n0 + ar, orow);
  }
  __syncthreads();

  // ---- GEMM2: h @ W2 -> feats (bufA) ----
  {
    f32x4 acc[4] = {};
    gemm16(acc, bufB, wbf + 65536 + wave * 4096, ar, kg, lane);
    epilogue_relu(acc, b2, bufA, n0 + ar, orow);
  }
  __syncthreads();

  // ---- GEMM3: feats @ Whp (N=512, 4 heads concat); wave w owns head w>>2 ----
  {
    const u16* __restrict__ Wp3 = wbf + 131072 + wave * 8192;
    f32x4 acc[4][2] = {};
#pragma unroll
    for (int kk = 0; kk < 8; ++kk) {
      const int k = kk * 32 + kg;
      bf16x8 a[4], b[2];
#pragma unroll
      for (int nb = 0; nb < 2; ++nb)
        b[nb] = *(const bf16x8*)&Wp3[((nb * 8 + kk) * 64 + lane) * 8];
#pragma unroll
      for (int m = 0; m < 4; ++m)
        a[m] = *(const bf16x8*)&bufA[(m * 16 + ar) * LDSW + k];
#pragma unroll
      for (int m = 0; m < 4; ++m)
#pragma unroll
        for (int nb = 0; nb < 2; ++nb)
          acc[m][nb] = __builtin_amdgcn_mfma_f32_16x16x32_bf16(a[m], b[nb], acc[m][nb], 0, 0, 0);
    }
    const int head = wave >> 2;
    const int c0   = (wave & 3) * 32;
#pragma unroll
    for (int nb = 0; nb < 2; ++nb) {
      const int acol = c0 + nb * 16 + ar;           // 0..127 within head
      const float bhv = bh[head * 128 + acol];
#pragma unroll
      for (int m = 0; m < 4; ++m) {
#pragma unroll
        for (int j = 0; j < 4; ++j) {
          const int row = m * 16 + orow + j;
          if (s_regime[row] == head)
            out_mean[(size_t)(row0 + row) * 128 + acol] = 0.1f * (acc[m][nb][j] + bhv);
        }
      }
    }
  }
}

extern "C" void kernel_launch(void* const* d_in, const int* in_sizes, int n_in,
                              void* d_out, int out_size, void* d_ws, size_t ws_size,
                              hipStream_t stream) {
  const float* x  = (const float*)d_in[0];
  const float* W1 = (const float*)d_in[1];
  const float* b1 = (const float*)d_in[2];
  const float* W2 = (const float*)d_in[3];
  const float* b2 = (const float*)d_in[4];
  const float* Wh = (const float*)d_in[5];
  const float* bh = (const float*)d_in[6];
  const float* ls = (const float*)d_in[7];

  const int B = in_sizes[0] / 256;          // 65536
  float* out_mean = (float*)d_out;
  float* out_std  = out_mean + (size_t)B * 128;
  u16* wbf = (u16*)d_ws;                    // needs 512 KiB

  hipLaunchKernelGGL(prep_weights, dim3(256), dim3(256), 0, stream, W1, W2, Wh, wbf);
  hipLaunchKernelGGL(actor_main, dim3(B / BM), dim3(THREADS), 0, stream,
                     x, b1, b2, bh, ls, wbf, out_mean, out_std);
}

// Round 10
// 66.666 us; speedup vs baseline: 3.3073x; 1.0624x over previous
//
#include <hip/hip_runtime.h>
#include <hip/hip_bf16.h>
#include <cstddef>

// ---------------------------------------------------------------------------
// HardActor: fused regime-routed MLP (bf16 MFMA end-to-end)
//   h     = relu(x @ W1 + b1)            [B,256]
//   feats = relu(h @ W2 + b2)            [B,256]
//   raw   = feats @ Wh[regime] + bh[regime]   (regime = (int)x[:,255])
//   mean  = 0.1 * raw ; std = clip(exp(log_std),1e-3,1) broadcast
//
// R10: R9 (swapped-operand GEMMs, D^T = W^T act^T; weights as A-frags from
// global, activations as B-frags from LDS; vectorized epilogues) with the
// s_regime LDS broadcast REMOVED. R9 passed first validation (2.4e-4) but
// diverged post-timing (4.4e-2) — a replay-only glitch consistent with a
// regime-routing visibility race. s_regime was the one 1-writer->all-readers
// LDS cell feeding store predicates; G3 now reads each row's regime directly
// from global x (L1/L2-hit, issued before the MFMA loop). All else identical.
// ---------------------------------------------------------------------------

typedef unsigned short u16;
typedef unsigned int   u32;

using bf16x8 = __attribute__((ext_vector_type(8))) __bf16;
using f32x4  = __attribute__((ext_vector_type(4))) float;

#define BM      64
#define LDSW    264   // 256 + 8 bf16 pad; 528B row pitch = 33*16B (b128-aligned)
#define THREADS 512

__device__ __forceinline__ u16 f2bf(float f) {
  return __builtin_bit_cast(u16, (__bf16)f);   // native v_cvt (RNE)
}

// Packed ws layout (u16 elements), A-frag order (A = W^T):
//  A-frag (16x16x32): lane l, elem j -> A[n = l&15][k = (l>>4)*8+j], i.e. W[k][n].
//  W1p [0)      : [w:8][nt:2][kk:8][lane:64][j:8]  (65536)
//                 n = w*32+nt*16+(l&15), k = kk*32+(l>>4)*8+j
//  W2p [65536)  : same
//  Whp [131072) : [w:8][ct:4][kk:8][lane:64][j:8]  (131072)
//                 c = w*64+ct*16+(l&15) in [0,512); head=c>>7, a=c&127
__global__ void prep_weights(const float* __restrict__ W1,
                             const float* __restrict__ W2,
                             const float* __restrict__ Wh,
                             u16* __restrict__ ws) {
  int i = blockIdx.x * 256 + threadIdx.x;          // [0, 65536)
  {
    int j  = i & 7, l = (i >> 3) & 63, kk = (i >> 9) & 7;
    int nt = (i >> 12) & 1, w = (i >> 13) & 7;
    int n = w * 32 + nt * 16 + (l & 15);
    int k = kk * 32 + ((l >> 4) << 3) + j;
    ws[i]         = f2bf(W1[k * 256 + n]);
    ws[65536 + i] = f2bf(W2[k * 256 + n]);
  }
#pragma unroll
  for (int t = 0; t < 2; ++t) {
    int idx = i + t * 65536;                        // [0, 131072)
    int j  = idx & 7, l = (idx >> 3) & 63, kk = (idx >> 9) & 7;
    int ct = (idx >> 12) & 3, w = (idx >> 14) & 7;
    int c = w * 64 + ct * 16 + (l & 15);            // col in [0,512)
    int k = kk * 32 + ((l >> 4) << 3) + j;
    ws[131072 + idx] = f2bf(Wh[(c >> 7) * 32768 + k * 128 + (c & 127)]);
  }
}

__device__ __forceinline__ f32x4 mfma16(bf16x8 a, bf16x8 b, f32x4 c) {
  return __builtin_amdgcn_mfma_f32_16x16x32_bf16(a, b, c, 0, 0, 0);
}

// One swapped layer: out^T[n][b] = sum_k W[k][n] act[b][k], n in wave's 32 cols.
// act, outbuf: LDS [64][LDSW] in [batch][feature] layout. Wp: wave's packed
// weights (global/L2). Writes relu(out+bias) as ds_write_b64.
__device__ __forceinline__ void gemm_swapped(const u16* __restrict__ act,
                                             const u16* __restrict__ Wp,
                                             const float* __restrict__ bias,
                                             u16* __restrict__ outbuf,
                                             int w, int ll, int lh, int lane) {
  f32x4 acc[2][4] = {};
#pragma unroll
  for (int kk = 0; kk < 8; ++kk) {
    bf16x8 a[2], b[4];
#pragma unroll
    for (int nt = 0; nt < 2; ++nt)
      a[nt] = *(const bf16x8*)&Wp[((nt * 8 + kk) * 64 + lane) * 8];
#pragma unroll
    for (int bt = 0; bt < 4; ++bt)
      b[bt] = *(const bf16x8*)&act[(bt * 16 + ll) * LDSW + kk * 32 + lh * 8];
#pragma unroll
    for (int nt = 0; nt < 2; ++nt)
#pragma unroll
      for (int bt = 0; bt < 4; ++bt)
        acc[nt][bt] = mfma16(a[nt], b[bt], acc[nt][bt]);
  }
#pragma unroll
  for (int nt = 0; nt < 2; ++nt) {
    const int n0 = w * 32 + nt * 16 + lh * 4;      // output feature base (4 consec)
    const float4 bv = *(const float4*)&bias[n0];
#pragma unroll
    for (int bt = 0; bt < 4; ++bt) {
      ushort4 o;
      o.x = f2bf(fmaxf(acc[nt][bt][0] + bv.x, 0.f));
      o.y = f2bf(fmaxf(acc[nt][bt][1] + bv.y, 0.f));
      o.z = f2bf(fmaxf(acc[nt][bt][2] + bv.z, 0.f));
      o.w = f2bf(fmaxf(acc[nt][bt][3] + bv.w, 0.f));
      *(ushort4*)&outbuf[(bt * 16 + ll) * LDSW + n0] = o;
    }
  }
}

__global__ __launch_bounds__(THREADS, 4) void actor_main(
    const float* __restrict__ x,
    const float* __restrict__ b1, const float* __restrict__ b2,
    const float* __restrict__ bh, const float* __restrict__ log_std,
    const u16* __restrict__ wbf,
    float* __restrict__ out_mean, float* __restrict__ out_std) {
  __shared__ u16 bufX[BM * LDSW];   // x (bf16), later feats
  __shared__ u16 bufH[BM * LDSW];   // h

  const int tid  = threadIdx.x;
  const int lane = tid & 63;
  const int w    = tid >> 6;           // wave 0..7
  const int ll   = lane & 15;          // batch-col within 16-tile
  const int lh   = lane >> 4;          // 0..3
  const int row0 = blockIdx.x * BM;

  // ---- stage x -> bf16 LDS [batch][feature] ----
  {
    const float4* xg = (const float4*)(x + (size_t)row0 * 256);
#pragma unroll
    for (int it = 0; it < 8; ++it) {               // 64 rows x 64 float4 / 512
      const int i = tid + it * THREADS;
      float4 v = xg[i];
      int row = i >> 6, c4 = (i & 63) << 2;
      ushort4 b;
      b.x = f2bf(v.x); b.y = f2bf(v.y); b.z = f2bf(v.z); b.w = f2bf(v.w);
      *(ushort4*)&bufX[row * LDSW + c4] = b;
    }
  }

  // ---- std writes (independent; overlap the barrier wait) ----
  {
    const int c4 = (tid & 31) << 2;
    float4 s;
    s.x = fminf(fmaxf(expf(log_std[c4 + 0]), 1e-3f), 1.0f);
    s.y = fminf(fmaxf(expf(log_std[c4 + 1]), 1e-3f), 1.0f);
    s.z = fminf(fmaxf(expf(log_std[c4 + 2]), 1e-3f), 1.0f);
    s.w = fminf(fmaxf(expf(log_std[c4 + 3]), 1e-3f), 1.0f);
#pragma unroll
    for (int i = tid; i < BM * 32; i += THREADS) {   // 4 iters
      int row = i >> 5;
      *(float4*)&out_std[(size_t)(row0 + row) * 128 + c4] = s;
    }
  }
  __syncthreads();

  // ---- G1: h^T = W1^T x^T  (reads bufX, writes bufH) ----
  gemm_swapped(bufX, wbf + w * 8192, b1, bufH, w, ll, lh, lane);
  __syncthreads();

  // ---- G2: feats^T = W2^T h^T  (reads bufH, writes bufX) ----
  gemm_swapped(bufH, wbf + 65536 + w * 8192, b2, bufX, w, ll, lh, lane);
  __syncthreads();

  // ---- G3: raw^T = Wh^T feats^T, 512 cols dense; wave w owns head w>>1.
  //      Regime read per-lane from global x (L1/L2 hit); direct global store. ----
  {
    const u16* __restrict__ Wp3 = wbf + 131072 + w * 16384;

    // per-lane regime for this lane's 4 batch rows (issued before MFMA loop)
    int rg[4];
#pragma unroll
    for (int bt = 0; bt < 4; ++bt)
      rg[bt] = (int)x[(size_t)(row0 + bt * 16 + ll) * 256 + 255];

    f32x4 acc[4][4] = {};
#pragma unroll
    for (int kk = 0; kk < 8; ++kk) {
      bf16x8 b[4];
#pragma unroll
      for (int bt = 0; bt < 4; ++bt)
        b[bt] = *(const bf16x8*)&bufX[(bt * 16 + ll) * LDSW + kk * 32 + lh * 8];
#pragma unroll
      for (int ct = 0; ct < 4; ++ct) {
        bf16x8 a = *(const bf16x8*)&Wp3[((ct * 8 + kk) * 64 + lane) * 8];
#pragma unroll
        for (int bt = 0; bt < 4; ++bt)
          acc[ct][bt] = mfma16(a, b[bt], acc[ct][bt]);
      }
    }
    const int head = w >> 1;
#pragma unroll
    for (int ct = 0; ct < 4; ++ct) {
      const int acol = (w & 1) * 64 + ct * 16 + lh * 4;   // 0..127, 4 consec
      const float4 bhv = *(const float4*)&bh[head * 128 + acol];
#pragma unroll
      for (int bt = 0; bt < 4; ++bt) {
        const int brow = bt * 16 + ll;
        if (rg[bt] == head) {
          float4 o;
          o.x = 0.1f * (acc[ct][bt][0] + bhv.x);
          o.y = 0.1f * (acc[ct][bt][1] + bhv.y);
          o.z = 0.1f * (acc[ct][bt][2] + bhv.z);
          o.w = 0.1f * (acc[ct][bt][3] + bhv.w);
          *(float4*)&out_mean[(size_t)(row0 + brow) * 128 + acol] = o;
        }
      }
    }
  }
}

extern "C" void kernel_launch(void* const* d_in, const int* in_sizes, int n_in,
                              void* d_out, int out_size, void* d_ws, size_t ws_size,
                              hipStream_t stream) {
  const float* x  = (const float*)d_in[0];
  const float* W1 = (const float*)d_in[1];
  const float* b1 = (const float*)d_in[2];
  const float* W2 = (const float*)d_in[3];
  const float* b2 = (const float*)d_in[4];
  const float* Wh = (const float*)d_in[5];
  const float* bh = (const float*)d_in[6];
  const float* ls = (const float*)d_in[7];

  const int B = in_sizes[0] / 256;          // 65536
  float* out_mean = (float*)d_out;
  float* out_std  = out_mean + (size_t)B * 128;
  u16* wbf = (u16*)d_ws;                    // needs 512 KiB

  hipLaunchKernelGGL(prep_weights, dim3(256), dim3(256), 0, stream, W1, W2, Wh, wbf);
  hipLaunchKernelGGL(actor_main, dim3(B / BM), dim3(THREADS), 0, stream,
                     x, b1, b2, bh, ls, wbf, out_mean, out_std);
}